// Round 1
// baseline (20532.626 us; speedup 1.0000x reference)
//
#include <hip/hip_runtime.h>

#define T_STEPS 512
#define E_EDGES 128
#define NN 32
#define HH 256
#define G4 1024   // 4*H
#define JB 8      // hidden channels owned per WG
#define NWG 64    // 2 dirs * 32 slots

__device__ __forceinline__ float fsig(float x) {
  x = fminf(fmaxf(x, -30.f), 30.f);
  return 1.f / (1.f + __expf(-x));
}
__device__ __forceinline__ float ftanh(float x) {
  float xc = fminf(fmaxf(x, -15.f), 15.f);
  float e = __expf(2.f * xc);
  return (e - 1.f) / (e + 1.f);
}

// ---------------- per-step edge counts (denominators) ----------------
__global__ __launch_bounds__(128) void count_kernel(const int* __restrict__ src,
    const int* __restrict__ dst, float* __restrict__ cS, float* __restrict__ cD) {
  __shared__ int ls[NN], ld[NN];
  int t = blockIdx.x;
  if (threadIdx.x < NN) { ls[threadIdx.x] = 0; ld[threadIdx.x] = 0; }
  __syncthreads();
  atomicAdd(&ls[src[t * E_EDGES + threadIdx.x]], 1);
  atomicAdd(&ld[dst[t * E_EDGES + threadIdx.x]], 1);
  __syncthreads();
  if (threadIdx.x < NN) {
    cS[t * NN + threadIdx.x] = (float)ls[threadIdx.x];
    cD[t * NN + threadIdx.x] = (float)ld[threadIdx.x];
  }
}

// ---------------- feed-forward gates GEMM -----------------------------
// Gx[lt][k][e] = b[k] + sum_m In[tsrc][e][m] * W[k][m]
template <int M>
__global__ __launch_bounds__(256) void gates_gemm(
    const float* __restrict__ In, const float* __restrict__ W,
    const float* __restrict__ b, float* __restrict__ Gx, int reverse, int t0) {
  __shared__ float Wsh[64][68];
  __shared__ float Xsh[128][68];
  const int tid = threadIdx.x;
  const int k0 = blockIdx.x * 64;
  const int lt = blockIdx.y;
  const int t = t0 + lt;
  const int tsrc = reverse ? (T_STEPS - 1 - t) : t;
  const float* Inb = In + (size_t)tsrc * E_EDGES * M;

  const int ty = tid >> 4;  // 0..15 -> k group
  const int tx = tid & 15;  // 0..15 -> e group (strided e = tx + 16*j)

  float acc[4][8];
#pragma unroll
  for (int i = 0; i < 4; ++i) {
    float bv = b[k0 + ty * 4 + i];
#pragma unroll
    for (int j = 0; j < 8; ++j) acc[i][j] = bv;
  }

  for (int m0 = 0; m0 < M; m0 += 64) {
    __syncthreads();
    // stage W tile 64x64
#pragma unroll
    for (int p = 0; p < 4; ++p) {
      int r = (tid >> 4) + 16 * p;
      int c4 = tid & 15;
      float4 v = *(const float4*)(W + (size_t)(k0 + r) * M + m0 + c4 * 4);
      *(float4*)(&Wsh[r][c4 * 4]) = v;
    }
    // stage X tile 128x64
#pragma unroll
    for (int p = 0; p < 8; ++p) {
      int r = (tid >> 4) + 16 * p;
      int c4 = tid & 15;
      float4 v = *(const float4*)(Inb + (size_t)r * M + m0 + c4 * 4);
      *(float4*)(&Xsh[r][c4 * 4]) = v;
    }
    __syncthreads();
#pragma unroll 8
    for (int mm = 0; mm < 64; ++mm) {
      float wv[4], xv[8];
#pragma unroll
      for (int i = 0; i < 4; ++i) wv[i] = Wsh[ty * 4 + i][mm];
#pragma unroll
      for (int j = 0; j < 8; ++j) xv[j] = Xsh[tx + 16 * j][mm];
#pragma unroll
      for (int i = 0; i < 4; ++i)
#pragma unroll
        for (int j = 0; j < 8; ++j) acc[i][j] = __fmaf_rn(wv[i], xv[j], acc[i][j]);
    }
  }
#pragma unroll
  for (int i = 0; i < 4; ++i) {
    size_t rowo = ((size_t)lt * G4 + (k0 + ty * 4 + i)) * E_EDGES;
#pragma unroll
    for (int j = 0; j < 8; ++j) Gx[rowo + tx + 16 * j] = acc[i][j];
  }
}

// ---------------- recurrence (cooperative, both directions) -----------
__global__ __launch_bounds__(256) void recur_kernel(
    const float* __restrict__ GxF, const float* __restrict__ GxB,
    const float* __restrict__ WhhF, const float* __restrict__ WhhB,
    const int* __restrict__ src, const int* __restrict__ dst,
    const float* __restrict__ cS, const float* __restrict__ cD,
    float* hnG, float* cnG, float* outBase,
    int t0, int nsteps, int roundBase, int* barCnt, int* barEpoch) {
  __shared__ float Ws[32][257];    // Whh slice rows g*8+jj
  __shared__ float hnS[32][132];   // staged hn half (128 cols)
  __shared__ float zP[2][32][33];  // z partials; zP[0] becomes final z
  __shared__ float cnL[32][9];
  __shared__ float hAcc[32][9];
  __shared__ float cAcc[32][9];
  __shared__ int sS[128], dS[128];
  __shared__ float cntLs[32];

  const int tid = threadIdx.x;
  const int wg = blockIdx.x;
  const int dir = wg >> 5;
  const int slot = wg & 31;
  const int j0 = slot * JB;
  const float* Gx = dir ? GxB : GxF;
  const float* Whh = dir ? WhhB : WhhF;
  float* hnGd = hnG + dir * NN * HH;
  float* cnGd = cnG + dir * NN * HH;

  // load Whh slice (rows g*256 + j0 + jj), once
  {
    int rl = tid >> 3;  // 0..31
    int g = rl >> 3, jj = rl & 7;
    const float* wrow = Whh + (size_t)(g * HH + j0 + jj) * HH;
    int c0 = tid & 7;
#pragma unroll
    for (int p = 0; p < 8; ++p) {
      int c4 = c0 + 8 * p;
      float4 v = *(const float4*)(wrow + c4 * 4);
      Ws[rl][c4 * 4 + 0] = v.x; Ws[rl][c4 * 4 + 1] = v.y;
      Ws[rl][c4 * 4 + 2] = v.z; Ws[rl][c4 * 4 + 3] = v.w;
    }
  }
  { // load cn, zero accumulators
    int n = tid >> 3, jj = tid & 7;
    cnL[n][jj] = cnGd[n * HH + j0 + jj];
    hAcc[n][jj] = 0.f; cAcc[n][jj] = 0.f;
  }
  __syncthreads();

  const int kq = tid >> 7;        // m-quarter within half
  const int ng = (tid >> 4) & 7;  // node group
  const int gg = tid & 15;        // gate-channel group
  const int n0 = ng * 4, gc0 = gg * 2;

  for (int rl_step = 0; rl_step < nsteps; ++rl_step) {
    const int r = t0 + rl_step;
    const int tr = T_STEPS - 1 - r;
    // stage src/dst/cnt for this step
    if (tid < 128) {
      const int* sp = dir ? (dst + (size_t)tr * E_EDGES) : (src + (size_t)r * E_EDGES);
      const int* dp = dir ? (src + (size_t)tr * E_EDGES) : (dst + (size_t)r * E_EDGES);
      sS[tid] = sp[tid];
      dS[tid] = dp[tid];
    } else if (tid < 160) {
      const float* cp = dir ? (cS + (size_t)tr * NN) : (cD + (size_t)r * NN);
      cntLs[tid - 128] = cp[tid - 128];
    }

    // ---- z = hn @ Whh_slice^T, accumulated over two K-halves ----
    float acc[4][2];
#pragma unroll
    for (int i = 0; i < 4; ++i) { acc[i][0] = 0.f; acc[i][1] = 0.f; }
#pragma unroll 1
    for (int h = 0; h < 2; ++h) {
      __syncthreads();
#pragma unroll
      for (int p = 0; p < 4; ++p) {
        int f4 = tid + 256 * p;  // 1024 float4 = 32x128 floats
        int n = f4 >> 5, c4 = f4 & 31;
        float4 v = *(const float4*)(hnGd + n * HH + h * 128 + c4 * 4);
        *(float4*)(&hnS[n][c4 * 4]) = v;
      }
      __syncthreads();
#pragma unroll 8
      for (int mq = 0; mq < 64; ++mq) {
        int mm = kq * 64 + mq;
        int mw = h * 128 + mm;
        float hv[4], wv[2];
#pragma unroll
        for (int i = 0; i < 4; ++i) hv[i] = hnS[n0 + i][mm];
#pragma unroll
        for (int j = 0; j < 2; ++j) wv[j] = Ws[gc0 + j][mw];
#pragma unroll
        for (int i = 0; i < 4; ++i)
#pragma unroll
          for (int j = 0; j < 2; ++j) acc[i][j] = __fmaf_rn(hv[i], wv[j], acc[i][j]);
      }
    }
#pragma unroll
    for (int i = 0; i < 4; ++i) {
      zP[kq][n0 + i][gc0 + 0] = acc[i][0];
      zP[kq][n0 + i][gc0 + 1] = acc[i][1];
    }
    __syncthreads();
#pragma unroll
    for (int p = 0; p < 4; ++p) {
      int o = tid + 256 * p;
      int n = o >> 5, gc = o & 31;
      zP[0][n][gc] += zP[1][n][gc];
    }
    __syncthreads();

    // ---- edge phase: gates -> cell -> per-edge h, scatter into LDS ----
    {
      const int e = tid >> 1, jh = tid & 1;
      const int se = sS[e], de = dS[e];
      const float* gxB = Gx + (size_t)rl_step * (G4 * E_EDGES) + e;
      float hq[4];
#pragma unroll
      for (int it = 0; it < 4; ++it) {
        int jj = jh * 4 + it;
        float gi = gxB[(size_t)(0 * HH + j0 + jj) * E_EDGES] + zP[0][se][0 + jj];
        float gf = gxB[(size_t)(1 * HH + j0 + jj) * E_EDGES] + zP[0][se][8 + jj];
        float gc_ = gxB[(size_t)(2 * HH + j0 + jj) * E_EDGES] + zP[0][se][16 + jj];
        float go = gxB[(size_t)(3 * HH + j0 + jj) * E_EDGES] + zP[0][se][24 + jj];
        float ig = fsig(gi), fg = fsig(gf), gt = ftanh(gc_), og = fsig(go);
        float cv = fg * cnL[se][jj] + ig * gt;
        float hv = og * ftanh(cv);
        hq[it] = hv;
        atomicAdd(&hAcc[de][jj], hv);
        atomicAdd(&cAcc[de][jj], cv);
      }
      int tw = dir ? tr : r;
      float4 h4 = make_float4(hq[0], hq[1], hq[2], hq[3]);
      *(float4*)(outBase + ((size_t)tw * E_EDGES + e) * 512 + dir * 256 + j0 + jh * 4) = h4;
    }
    __syncthreads();

    // ---- scatter-mean -> new node state ----
    {
      int n = tid >> 3, jj = tid & 7;
      float denom = fmaxf(cntLs[n], 1.f);
      float hnv = hAcc[n][jj] / denom;
      float cnv = cAcc[n][jj] / denom;
      hnGd[n * HH + j0 + jj] = hnv;
      cnL[n][jj] = cnv;
      hAcc[n][jj] = 0.f; cAcc[n][jj] = 0.f;
    }

    // ---- grid barrier (epoch-based) ----
    __threadfence();
    __syncthreads();
    if (tid == 0) {
      int target = roundBase + rl_step + 1;
      int arrived = __hip_atomic_fetch_add(barCnt, 1, __ATOMIC_ACQ_REL, __HIP_MEMORY_SCOPE_AGENT);
      if (arrived == NWG - 1) {
        __hip_atomic_store(barCnt, 0, __ATOMIC_RELAXED, __HIP_MEMORY_SCOPE_AGENT);
        __hip_atomic_store(barEpoch, target, __ATOMIC_RELEASE, __HIP_MEMORY_SCOPE_AGENT);
      } else {
        int guard = 0;
        while (__hip_atomic_load(barEpoch, __ATOMIC_ACQUIRE, __HIP_MEMORY_SCOPE_AGENT) < target) {
          __builtin_amdgcn_s_sleep(2);
          if (++guard > (1 << 22)) break;  // bail out instead of hanging
        }
      }
    }
    __syncthreads();
  }
  // persist cell state for next chunk
  {
    int n = tid >> 3, jj = tid & 7;
    cnGd[n * HH + j0 + jj] = cnL[n][jj];
  }
}

// ---------------- host launcher ---------------------------------------
extern "C" void kernel_launch(void* const* d_in, const int* in_sizes, int n_in,
                              void* d_out, int out_size, void* d_ws, size_t ws_size,
                              hipStream_t stream) {
  const float* x = (const float*)d_in[0];
  const float* Wih0 = (const float*)d_in[1];
  const float* Whh0 = (const float*)d_in[2];
  const float* b0 = (const float*)d_in[3];
  const float* Wih1 = (const float*)d_in[4];
  const float* Whh1 = (const float*)d_in[5];
  const float* b1 = (const float*)d_in[6];
  const int* src = (const int*)d_in[7];
  const int* dst = (const int*)d_in[8];
  float* out = (float*)d_out;

  const size_t outElems = (size_t)T_STEPS * E_EDGES * 512;
  int C = 512;
  while (C >= 1) {
    size_t need = (2 * (size_t)C * G4 * E_EDGES + outElems + 4 * (size_t)NN * HH +
                   2 * (size_t)T_STEPS * NN + 64) * sizeof(float);
    if (need <= ws_size) break;
    C >>= 1;
  }
  if (C < 1) return;  // workspace too small; nothing we can do

  float* GxF = (float*)d_ws;
  float* GxB = GxF + (size_t)C * G4 * E_EDGES;
  float* out0 = GxB + (size_t)C * G4 * E_EDGES;
  float* hnG = out0 + outElems;
  float* cnG = hnG + 2 * NN * HH;
  float* cSt = cnG + 2 * NN * HH;
  float* cDt = cSt + (size_t)T_STEPS * NN;
  int* bar = (int*)(cDt + (size_t)T_STEPS * NN);

  hipMemsetAsync(bar, 0, 2 * sizeof(int), stream);
  count_kernel<<<dim3(T_STEPS), 128, 0, stream>>>(src, dst, cSt, cDt);

  for (int layer = 0; layer < 2; ++layer) {
    const float* Wih = layer ? Wih1 : Wih0;
    const float* Whh = layer ? Whh1 : Whh0;
    const float* bb = layer ? b1 : b0;
    const float* In = layer ? out0 : x;
    float* outT = layer ? out : out0;
    hipMemsetAsync(hnG, 0, 2 * NN * HH * sizeof(float), stream);
    hipMemsetAsync(cnG, 0, 2 * NN * HH * sizeof(float), stream);
    for (int t0 = 0; t0 < T_STEPS; t0 += C) {
      if (layer == 0) {
        gates_gemm<64><<<dim3(16, C), 256, 0, stream>>>(In, Wih, bb, GxF, 0, t0);
        gates_gemm<64><<<dim3(16, C), 256, 0, stream>>>(In, Wih + (size_t)G4 * 64, bb + G4, GxB, 1, t0);
      } else {
        gates_gemm<512><<<dim3(16, C), 256, 0, stream>>>(In, Wih, bb, GxF, 0, t0);
        gates_gemm<512><<<dim3(16, C), 256, 0, stream>>>(In, Wih + (size_t)G4 * 512, bb + G4, GxB, 1, t0);
      }
      const float* gxF = GxF; const float* gxB = GxB;
      const float* whF = Whh; const float* whB = Whh + (size_t)G4 * HH;
      const int* psrc = src; const int* pdst = dst;
      const float* pcS = cSt; const float* pcD = cDt;
      float* phn = hnG; float* pcn = cnG; float* pout = outT;
      int a_t0 = t0, a_ns = C, a_rb = layer * T_STEPS + t0;
      int* pbc = bar; int* pbe = bar + 1;
      void* args[16] = {&gxF, &gxB, &whF, &whB, &psrc, &pdst, &pcS, &pcD,
                        &phn, &pcn, &pout, &a_t0, &a_ns, &a_rb, &pbc, &pbe};
      hipLaunchCooperativeKernel((const void*)recur_kernel, dim3(NWG), dim3(256),
                                 args, 0, stream);
    }
  }
}